// Round 1
// baseline (93.612 us; speedup 1.0000x reference)
//
#include <hip/hip_runtime.h>
#include <math.h>

#define B_ 256
#define V_ 4096
#define K_ 64
#define VK (V_*K_)
#define MINI 1e-6f

// ---- output layout (floats, concatenated in reference return order) ----
#define TEN_OFF 0                         // temp_exp_n [V,K]
#define TEM_OFF (V_*K_)                   // temp_exp_m [B,K]   = 262144
#define QZ_OFF  (TEM_OFF + B_*K_)         // exp_q_z scalar     = 278528
#define NEN_OFF (QZ_OFF + 1)              // new_exp_n [V,K]    = 278529 (odd!)
#define NEM_OFF (NEN_OFF + V_*K_)         // new_exp_m [B,K]    = 540673 (odd!)

// ---- workspace layout; ws is 256 MB ----
// float-indexed:
#define WS_PART 128                       // den partials [64 groups][64 k]
#define WS_ENT  4352                      // per-block entropy partials [256]
// f16(short)-indexed (byte offset 32768, clear of WS_ENT which ends at byte 18432):
#define WS_TENP_S 16384                   // ten partials f16 [4 bt][V,K]
#define WS_TEMP_S (WS_TENP_S + 4*VK)      // tem partials f16 [256 blk][64 b][64 k]

#define LDB 72                            // bf16 LDS row stride (shorts)

typedef __attribute__((ext_vector_type(8))) short bf16x8;
typedef __attribute__((ext_vector_type(4))) float f32x4;
typedef _Float16 f16;
typedef __attribute__((ext_vector_type(4))) _Float16 f16x4;

__device__ __forceinline__ short bf(float x) {
    return (short)(__float_as_uint(x) >> 16);   // truncate f32 -> bf16
}
__device__ __forceinline__ float bf2f(short s) {
    return __uint_as_float(((unsigned int)(unsigned short)s) << 16);
}

__device__ __forceinline__ int detect_is64(const int* bi) {
    int any = 0;
#pragma unroll
    for (int i = 1; i < 64; i += 2) any |= bi[i];
    return any == 0;
}

__device__ __forceinline__ float wave_sum64(float x) {
    x += __shfl_xor(x, 1);
    x += __shfl_xor(x, 2);
    x += __shfl_xor(x, 4);
    x += __shfl_xor(x, 8);
    x += __shfl_xor(x, 16);
    x += __shfl_xor(x, 32);
    return x;
}

__device__ __forceinline__ bf16x8 ldfrag(const short* arr, int row, int kofs) {
    return *(const bf16x8*)&arr[row * LDB + kofs];
}

// ---------------------------------------------------------------------------
// k_pre (grid 64 x 256): den partials (coalesced). Scalars moved to k_post.
// ---------------------------------------------------------------------------
__global__ __launch_bounds__(256) void k_pre(
    const float* __restrict__ beta, const float* __restrict__ exp_n,
    float* __restrict__ ws)
{
    const int blk = blockIdx.x, tid = threadIdx.x;
    __shared__ float red[256];
    const int k = tid & 63, sub = tid >> 6;
    float p = 0.f;
#pragma unroll
    for (int i = 0; i < 16; i++) {
        const int v = blk * 64 + sub * 16 + i;
        p += beta[v * K_ + k] + exp_n[v * K_ + k];
    }
    red[tid] = p;
    __syncthreads();
    if (tid < 64)
        ws[WS_PART + blk * 64 + tid] =
            red[tid] + red[64 + tid] + red[128 + tid] + red[192 + tid];
}

// ---------------------------------------------------------------------------
// k_main (grid 256 = 4 bt x 64 vt, 256 thr = 4 waves): MFMA path, no atomics.
// Partials now stored as f16 (halves ws round-trip traffic vs f32).
// ---------------------------------------------------------------------------
__global__ __launch_bounds__(256, 2) void k_main(
    const int* __restrict__ BOW, const int* __restrict__ bidx,
    const float* __restrict__ alpha, const float* __restrict__ pi,
    const float* __restrict__ exp_m, const float* __restrict__ beta,
    const float* __restrict__ exp_n,
    float* __restrict__ ws)
{
    __shared__ __align__(16) short th_b [64 * LDB];   // bf16 theta[b][k]
    __shared__ __align__(16) short thl_b[64 * LDB];   // bf16 th*log(th)
    __shared__ __align__(16) short ph_b [64 * LDB];   // bf16 phi[v][k]
    __shared__ __align__(16) short phl_b[64 * LDB];   // bf16 ph*log(ph)
    __shared__ __align__(16) short tht_b[64 * LDB];   // bf16 theta^T[k][b]
    __shared__ __align__(16) short pht_b[64 * LDB];   // bf16 phi^T[k][v]
    __shared__ __align__(16) short W_b  [64 * LDB];   // bf16 W[b][v]
    __shared__ __align__(16) short Wt_b [64 * LDB];   // bf16 W^T[v][b]
    __shared__ unsigned char cnt_s[64 * 65];
    __shared__ float dred[256];
    __shared__ float rden_s[64];
    __shared__ float entw[4];
    __shared__ int is64s;
    const int tid = threadIdx.x;
    const int vt = blockIdx.x & 63, bt = blockIdx.x >> 6;
    const int b0 = bt * 64, v0 = vt * 64;
    f16* __restrict__ wsH = (f16*)ws;

    // ---- den[k] from coalesced partials ----
    if (tid == 0) is64s = detect_is64(bidx);
    {
        const int k = tid & 63, g0 = tid >> 6;
        float s = 0.f;
#pragma unroll
        for (int i = 0; i < 16; i++)
            s += ws[WS_PART + (g0 + 4 * i) * 64 + k];
        dred[tid] = s;
    }
    __syncthreads();
    if (tid < 64)
        rden_s[tid] = __builtin_amdgcn_rcpf(
            dred[tid] + dred[64 + tid] + dred[128 + tid] + dred[192 + tid]);
    __syncthreads();

    {   // ---- staging: row r (0..63), 16-col chunk q (0..3) ----
        const int r = tid >> 2, q = tid & 3;
        const int idx = is64s ? bidx[2 * (b0 + r)] : bidx[b0 + r];
        const int v = v0 + r;
#pragma unroll
        for (int c4 = 0; c4 < 4; c4++) {
            const int k = q * 16 + c4 * 4;
            const float4 a4 = *(const float4*)&alpha[k];
            const float4 p4 = *(const float4*)&pi[idx * K_ + k];
            const float4 m4 = *(const float4*)&exp_m[idx * K_ + k];
            float4 t, tl;
            t.x = a4.x * p4.x + m4.x;  tl.x = t.x * __logf(t.x);
            t.y = a4.y * p4.y + m4.y;  tl.y = t.y * __logf(t.y);
            t.z = a4.z * p4.z + m4.z;  tl.z = t.z * __logf(t.z);
            t.w = a4.w * p4.w + m4.w;  tl.w = t.w * __logf(t.w);
            *(short4*)&th_b [r * LDB + k] = make_short4(bf(t.x), bf(t.y), bf(t.z), bf(t.w));
            *(short4*)&thl_b[r * LDB + k] = make_short4(bf(tl.x), bf(tl.y), bf(tl.z), bf(tl.w));
            tht_b[(k + 0) * LDB + r] = bf(t.x);
            tht_b[(k + 1) * LDB + r] = bf(t.y);
            tht_b[(k + 2) * LDB + r] = bf(t.z);
            tht_b[(k + 3) * LDB + r] = bf(t.w);
            const float4 b4 = *(const float4*)&beta[v * K_ + k];
            const float4 e4 = *(const float4*)&exp_n[v * K_ + k];
            const float4 d4 = *(const float4*)&rden_s[k];
            float4 p, pl;
            p.x = (b4.x + e4.x) * d4.x;  pl.x = p.x * __logf(p.x);
            p.y = (b4.y + e4.y) * d4.y;  pl.y = p.y * __logf(p.y);
            p.z = (b4.z + e4.z) * d4.z;  pl.z = p.z * __logf(p.z);
            p.w = (b4.w + e4.w) * d4.w;  pl.w = p.w * __logf(p.w);
            *(short4*)&ph_b [r * LDB + k] = make_short4(bf(p.x), bf(p.y), bf(p.z), bf(p.w));
            *(short4*)&phl_b[r * LDB + k] = make_short4(bf(pl.x), bf(pl.y), bf(pl.z), bf(pl.w));
            pht_b[(k + 0) * LDB + r] = bf(p.x);
            pht_b[(k + 1) * LDB + r] = bf(p.y);
            pht_b[(k + 2) * LDB + r] = bf(p.z);
            pht_b[(k + 3) * LDB + r] = bf(p.w);
            const int4 cc = *(const int4*)&BOW[(b0 + r) * V_ + v0 + k];
            cnt_s[r * 65 + k + 0] = (unsigned char)cc.x;
            cnt_s[r * 65 + k + 1] = (unsigned char)cc.y;
            cnt_s[r * 65 + k + 2] = (unsigned char)cc.z;
            cnt_s[r * 65 + k + 3] = (unsigned char)cc.w;
        }
    }
    __syncthreads();

    const int lane = tid & 63, wv = tid >> 6;
    const int l15 = lane & 15, quad = lane >> 4;
    const int qk = quad * 8;                  // k-offset within frag

    // ---- S/E GEMM (MFMA) + W + entropy; wave wv owns b-rows [wv*16, +16) ----
    {
        const int mb = wv * 16;
        const bf16x8 a_t0 = ldfrag(th_b,  mb + l15, 0  + qk);
        const bf16x8 a_t1 = ldfrag(th_b,  mb + l15, 32 + qk);
        const bf16x8 a_l0 = ldfrag(thl_b, mb + l15, 0  + qk);
        const bf16x8 a_l1 = ldfrag(thl_b, mb + l15, 32 + qk);
        float entacc = 0.f;
#pragma unroll
        for (int j = 0; j < 4; j++) {
            const int vrow = j * 16 + l15;
            const bf16x8 b_p0 = ldfrag(ph_b,  vrow, 0  + qk);
            const bf16x8 b_p1 = ldfrag(ph_b,  vrow, 32 + qk);
            const bf16x8 b_l0 = ldfrag(phl_b, vrow, 0  + qk);
            const bf16x8 b_l1 = ldfrag(phl_b, vrow, 32 + qk);
            f32x4 sa = {0.f, 0.f, 0.f, 0.f};
            f32x4 ea = {0.f, 0.f, 0.f, 0.f};
            sa = __builtin_amdgcn_mfma_f32_16x16x32_bf16(a_t0, b_p0, sa, 0, 0, 0);
            sa = __builtin_amdgcn_mfma_f32_16x16x32_bf16(a_t1, b_p1, sa, 0, 0, 0);
            ea = __builtin_amdgcn_mfma_f32_16x16x32_bf16(a_l0, b_p0, ea, 0, 0, 0);
            ea = __builtin_amdgcn_mfma_f32_16x16x32_bf16(a_l1, b_p1, ea, 0, 0, 0);
            ea = __builtin_amdgcn_mfma_f32_16x16x32_bf16(a_t0, b_l0, ea, 0, 0, 0);
            ea = __builtin_amdgcn_mfma_f32_16x16x32_bf16(a_t1, b_l1, ea, 0, 0, 0);
#pragma unroll
            for (int reg = 0; reg < 4; reg++) {
                const int b = mb + quad * 4 + reg;    // D row
                const int v = j * 16 + l15;           // D col
                const float s = sa[reg];
                const float sm = s + MINI;
                const float rr = __builtin_amdgcn_rcpf(sm);
                const int c = (int)cnt_s[b * 65 + v];
                const float w = (float)c * rr;
                W_b [b * LDB + v] = bf(w);
                Wt_b[v * LDB + b] = bf(w);
                if (c) entacc += (ea[reg] - s * __logf(sm)) * rr;
            }
        }
        entacc = wave_sum64(entacc);
        if (lane == 0) entw[wv] = entacc;
    }
    __syncthreads();   // W/Wt published; entw published
    if (tid == 0)
        ws[WS_ENT + blockIdx.x] = entw[0] + entw[1] + entw[2] + entw[3];

    // ---- ten GEMM: D[v,k] = sum_b Wt[v,b]*theta[b,k]; wave owns v-rows ----
    {
        const int mv = wv * 16;
        const bf16x8 wa0 = ldfrag(Wt_b, mv + l15, 0  + qk);
        const bf16x8 wa1 = ldfrag(Wt_b, mv + l15, 32 + qk);
#pragma unroll
        for (int j = 0; j < 4; j++) {
            const bf16x8 bt0 = ldfrag(tht_b, j * 16 + l15, 0  + qk);
            const bf16x8 bt1 = ldfrag(tht_b, j * 16 + l15, 32 + qk);
            f32x4 acc = {0.f, 0.f, 0.f, 0.f};
            acc = __builtin_amdgcn_mfma_f32_16x16x32_bf16(wa0, bt0, acc, 0, 0, 0);
            acc = __builtin_amdgcn_mfma_f32_16x16x32_bf16(wa1, bt1, acc, 0, 0, 0);
#pragma unroll
            for (int reg = 0; reg < 4; reg++) {
                const int v = mv + quad * 4 + reg;
                const int kc = j * 16 + l15;
                wsH[WS_TENP_S + bt * VK + (v0 + v) * K_ + kc] =
                    (f16)(acc[reg] * bf2f(ph_b[v * LDB + kc]));
            }
        }
    }

    // ---- tem GEMM: D[b,k] = sum_v W[b,v]*phi[v,k]; wave owns b-rows ----
    {
        const int mb = wv * 16;
        const bf16x8 wa0 = ldfrag(W_b, mb + l15, 0  + qk);
        const bf16x8 wa1 = ldfrag(W_b, mb + l15, 32 + qk);
#pragma unroll
        for (int j = 0; j < 4; j++) {
            const bf16x8 bp0 = ldfrag(pht_b, j * 16 + l15, 0  + qk);
            const bf16x8 bp1 = ldfrag(pht_b, j * 16 + l15, 32 + qk);
            f32x4 acc = {0.f, 0.f, 0.f, 0.f};
            acc = __builtin_amdgcn_mfma_f32_16x16x32_bf16(wa0, bp0, acc, 0, 0, 0);
            acc = __builtin_amdgcn_mfma_f32_16x16x32_bf16(wa1, bp1, acc, 0, 0, 0);
#pragma unroll
            for (int reg = 0; reg < 4; reg++) {
                const int b = mb + quad * 4 + reg;
                const int kc = j * 16 + l15;
                wsH[WS_TEMP_S + blockIdx.x * 4096 + b * K_ + kc] =
                    (f16)(acc[reg] * bf2f(th_b[b * LDB + kc]));
            }
        }
    }
}

// ---------------------------------------------------------------------------
// k_post (grid 321 x 256): reductions + epilogues, no atomics.
// Reads f16 partials; computes rho/scale locally (cheap, deterministic).
// ---------------------------------------------------------------------------
__global__ __launch_bounds__(256) void k_post(
    const int* __restrict__ bidx, const float* __restrict__ exp_n,
    const float* __restrict__ exp_m,
    const int* __restrict__ iterp, const int* __restrict__ cmp,
    const int* __restrict__ bcp,
    const float* __restrict__ ws, float* __restrict__ out)
{
    const int blk = blockIdx.x, tid = threadIdx.x;
    const f16* __restrict__ wsH = (const f16*)ws;
    if (blk < 256) {
        const float rho = powf((float)(iterp[0] + 5), -0.9f);
        const int t = blk * 256 + tid;              // float4 idx < 65536
        const f16x4 p0 = *(const f16x4*)&wsH[WS_TENP_S + 0 * VK + t * 4];
        const f16x4 p1 = *(const f16x4*)&wsH[WS_TENP_S + 1 * VK + t * 4];
        const f16x4 p2 = *(const f16x4*)&wsH[WS_TENP_S + 2 * VK + t * 4];
        const f16x4 p3 = *(const f16x4*)&wsH[WS_TENP_S + 3 * VK + t * 4];
        float4 s;
        s.x = ((float)p0.x + (float)p1.x) + ((float)p2.x + (float)p3.x);
        s.y = ((float)p0.y + (float)p1.y) + ((float)p2.y + (float)p3.y);
        s.z = ((float)p0.z + (float)p1.z) + ((float)p2.z + (float)p3.z);
        s.w = ((float)p0.w + (float)p1.w) + ((float)p2.w + (float)p3.w);
        *(float4*)&out[TEN_OFF + t * 4] = s;
        const float4 e4 = *(const float4*)&exp_n[t * 4];
        const float rs = rho * ((float)cmp[0] / (float)bcp[0]);
        out[NEN_OFF + t * 4 + 0] = (1.f - rho) * e4.x + rs * s.x;
        out[NEN_OFF + t * 4 + 1] = (1.f - rho) * e4.y + rs * s.y;
        out[NEN_OFF + t * 4 + 2] = (1.f - rho) * e4.z + rs * s.z;
        out[NEN_OFF + t * 4 + 3] = (1.f - rho) * e4.w + rs * s.w;
    } else if (blk < 320) {
        __shared__ int is64s;
        if (tid == 0) is64s = detect_is64(bidx);
        __syncthreads();
        const float rho = powf((float)(iterp[0] + 5), -0.9f);
        const int b = (blk - 256) * 4 + (tid >> 6);  // < 256
        const int k = tid & 63;
        const int bt = b >> 6, r = b & 63;
        float s = 0.f;
#pragma unroll 8
        for (int vt = 0; vt < 64; vt++)
            s += (float)wsH[WS_TEMP_S + (vt * 4 + bt) * 4096 + r * K_ + k];
        out[TEM_OFF + b * K_ + k] = s;
        const int idx = is64s ? bidx[2 * b] : bidx[b];
        out[NEM_OFF + b * K_ + k] =
            (1.f - rho) * exp_m[idx * K_ + k] + rho * s;
    } else {
        __shared__ float red[256];
        red[tid] = ws[WS_ENT + tid];
        __syncthreads();
        for (int s = 128; s > 0; s >>= 1) {
            if (tid < s) red[tid] += red[tid + s];
            __syncthreads();
        }
        if (tid == 0) out[QZ_OFF] = red[0];
    }
}

extern "C" void kernel_launch(void* const* d_in, const int* in_sizes, int n_in,
                              void* d_out, int out_size, void* d_ws, size_t ws_size,
                              hipStream_t stream)
{
    const int*   BOW   = (const int*)d_in[0];
    const int*   bidx  = (const int*)d_in[1];
    const float* alpha = (const float*)d_in[2];
    const float* pi    = (const float*)d_in[3];
    const float* exp_m = (const float*)d_in[4];
    const float* beta  = (const float*)d_in[5];
    const float* exp_n = (const float*)d_in[6];
    const int*   iterp = (const int*)d_in[7];
    const int*   cmp   = (const int*)d_in[8];
    const int*   bcp   = (const int*)d_in[9];
    float* out = (float*)d_out;
    float* ws  = (float*)d_ws;

    hipLaunchKernelGGL(k_pre, dim3(64), dim3(256), 0, stream,
                       beta, exp_n, ws);
    hipLaunchKernelGGL(k_main, dim3(256), dim3(256), 0, stream,
                       BOW, bidx, alpha, pi, exp_m, beta, exp_n, ws);
    hipLaunchKernelGGL(k_post, dim3(321), dim3(256), 0, stream,
                       bidx, exp_n, exp_m, iterp, cmp, bcp, ws, out);
}